// Round 8
// baseline (230.702 us; speedup 1.0000x reference)
//
#include <hip/hip_runtime.h>
#include <math.h>

#define NUM_EXPERTS 8
#define CAPACITY 320
#define NGROUP 8
#define NTOK 2048
#define HID 2048
#define NTOKENS (NGROUP * NTOK)  // 16384

typedef float vfloat4 __attribute__((ext_vector_type(4)));  // native vector:
// __builtin_nontemporal_load requires scalar/native-vector, not HIP_vector_type.

// Kernel A: router logits + softmax max + argmax — split-K x2 for occupancy.
//
// R7 (2 tokens x 32-lane teams, 16 waves/CU) landed ~63 us: latency-bound,
// in-flight hs bytes/CU ~ waves/CU x hs-queue-fraction. Token-parallelism
// caps at 4096 waves (16/CU) for 4 tokens/wave, so: SPLIT-K. Each wave
// computes HALF of H for its 4 tokens (same 2-hs : 8-W queue ratio, same
// register shape); the two K-halves combine through 1 KB of LDS. Grid 2048
// x 4 waves = 8192 waves = 32 waves/CU — IF VGPR <= 64 (R6's identical
// idiom with half the acc footprint compiled to VGPR=32; if >64 we stay at
// 16 waves/CU = R7-neutral).
//
// Spill discipline (R3/R5/R6-proven): inline load->consume ONLY, no staging
// arrays, no __launch_bounds__. hs loads nontemporal (zero reuse) so W
// (64 KB > 32 KB L1) keeps L1 residency.
//
// fp64 accumulation; per-half lane order is R7's (q = i*32 + c within the
// half); halves summed in fp64 -> logits differ from R7 by ~1e-13 ->
// absmax/argmax unchanged (verified 0.0039 five rounds running).
__global__ void router_logits_kernel(
    const float* __restrict__ hs, const float* __restrict__ Wt,
    const float* __restrict__ bias,
    float* __restrict__ out_logits, float* __restrict__ out_pmax,
    int* __restrict__ ws_idx)
{
    __shared__ double part[8][NUM_EXPERTS][2];  // [local tok][expert][k-half]

    const int tid   = threadIdx.x;
    const int c     = tid & 31;          // lane within 32-lane team
    const int w     = tid >> 6;          // wave 0..3
    const int kh    = w >> 1;            // k-half 0/1
    const int wt    = w & 1;             // token-group within half
    const int tteam = (tid >> 5) & 1;    // team within wave
    const int tlA   = (wt * 2 + tteam) * 2;  // local token 0,2,4,6
    const int tokbase = blockIdx.x * 8;
    const int tokA  = tokbase + tlA;
    const int tokB  = tokA + 1;

    const vfloat4* hsA = (const vfloat4*)(hs + (size_t)tokA * HID);
    const vfloat4* hsB = (const vfloat4*)(hs + (size_t)tokB * HID);
    const vfloat4* Wv  = (const vfloat4*)Wt;

    double accA[NUM_EXPERTS], accB[NUM_EXPERTS];
#pragma unroll
    for (int e = 0; e < NUM_EXPERTS; ++e) { accA[e] = 0.0; accB[e] = 0.0; }

    const int qbase = kh * 256;  // half of H/4 = 512 float4 per row

#pragma unroll 4
    for (int i = 0; i < 8; ++i) {
        const int q = qbase + i * 32 + c;
        vfloat4 a = __builtin_nontemporal_load(&hsA[q]);
        vfloat4 b = __builtin_nontemporal_load(&hsB[q]);
        double ax = (double)a.x, ay = (double)a.y;
        double az = (double)a.z, aw = (double)a.w;
        double bx = (double)b.x, by = (double)b.y;
        double bz = (double)b.z, bw = (double)b.w;
#pragma unroll
        for (int e = 0; e < NUM_EXPERTS; ++e) {
            vfloat4 wv = Wv[e * (HID / 4) + q];
            double wx = (double)wv.x, wy = (double)wv.y;
            double wz = (double)wv.z, ww = (double)wv.w;
            accA[e] += ax * wx + ay * wy + az * wz + aw * ww;
            accB[e] += bx * wx + by * wy + bz * wz + bw * ww;
        }
    }

    // Butterfly over the 5 chunk bits (teams are aligned 32-lane groups).
#pragma unroll
    for (int m = 1; m < 32; m <<= 1) {
#pragma unroll
        for (int e = 0; e < NUM_EXPERTS; ++e) {
            accA[e] += __shfl_xor(accA[e], m, 64);
            accB[e] += __shfl_xor(accB[e], m, 64);
        }
    }

    if (c == 0) {
#pragma unroll
        for (int e = 0; e < NUM_EXPERTS; ++e) {
            part[tlA][e][kh]     = accA[e];
            part[tlA + 1][e][kh] = accB[e];
        }
    }
    __syncthreads();

    if (tid < 8) {
        const int t   = tid;
        const int tok = tokbase + t;
        float lf[NUM_EXPERTS];
#pragma unroll
        for (int e = 0; e < NUM_EXPERTS; ++e)
            lf[e] = (float)((part[t][e][0] + part[t][e][1]) + (double)bias[e]);
        // first-occurrence argmax (matches jnp.argmax tie-break)
        float mx = lf[0];
        int idx = 0;
#pragma unroll
        for (int e = 1; e < NUM_EXPERTS; ++e)
            if (lf[e] > mx) { mx = lf[e]; idx = e; }
        float sum = 0.0f;
#pragma unroll
        for (int e = 0; e < NUM_EXPERTS; ++e)
            sum += expf(lf[e] - mx);
        float4* lp = (float4*)(out_logits + (size_t)tok * NUM_EXPERTS);
        lp[0] = make_float4(lf[0], lf[1], lf[2], lf[3]);
        lp[1] = make_float4(lf[4], lf[5], lf[6], lf[7]);
        out_pmax[tok] = 1.0f / sum;  // exp(mx-mx)/sum
        ws_idx[tok] = idx;
    }
}

// Kernel B: per-group inclusive cumsum of one-hot expert assignment + capacity
// mask. One block per group; thread tid owns tokens [tid*8, tid*8+8). Counts
// packed 16-bit x8 into 4 uint32 words; Hillis-Steele scan in LDS.
__global__ __launch_bounds__(256) void router_scan_kernel(
    const int* __restrict__ ws_idx, float* __restrict__ out_expert)
{
    __shared__ unsigned sb[4][256];
    const int g    = blockIdx.x;
    const int tid  = threadIdx.x;
    const int tok0 = g * NTOK + tid * 8;

    int idx[8];
#pragma unroll
    for (int j = 0; j < 8; ++j) idx[j] = ws_idx[tok0 + j];

    unsigned lc[4] = {0u, 0u, 0u, 0u};
#pragma unroll
    for (int j = 0; j < 8; ++j)
        lc[idx[j] >> 1] += 1u << ((idx[j] & 1) * 16);

#pragma unroll
    for (int w = 0; w < 4; ++w) sb[w][tid] = lc[w];
    __syncthreads();

    for (int off = 1; off < 256; off <<= 1) {
        unsigned v[4];
#pragma unroll
        for (int w = 0; w < 4; ++w)
            v[w] = (tid >= off) ? sb[w][tid - off] : 0u;
        __syncthreads();
#pragma unroll
        for (int w = 0; w < 4; ++w) sb[w][tid] += v[w];
        __syncthreads();
    }

    // exclusive prefix counts per expert (inclusive - local)
    unsigned run[NUM_EXPERTS];
#pragma unroll
    for (int e = 0; e < NUM_EXPERTS; ++e)
        run[e] = ((sb[e >> 1][tid] - lc[e >> 1]) >> ((e & 1) * 16)) & 0xFFFFu;

#pragma unroll
    for (int j = 0; j < 8; ++j) {
        const int e = idx[j];
        run[e] += 1u;  // inclusive token_priority for this token's expert
        const float keep = (run[e] <= CAPACITY) ? 1.0f : 0.0f;
        float vv[NUM_EXPERTS];
#pragma unroll
        for (int k = 0; k < NUM_EXPERTS; ++k)
            vv[k] = (k == e) ? keep : 0.0f;
        float4* op = (float4*)(out_expert + (size_t)(tok0 + j) * NUM_EXPERTS);
        op[0] = make_float4(vv[0], vv[1], vv[2], vv[3]);
        op[1] = make_float4(vv[4], vv[5], vv[6], vv[7]);
    }
}

extern "C" void kernel_launch(void* const* d_in, const int* in_sizes, int n_in,
                              void* d_out, int out_size, void* d_ws, size_t ws_size,
                              hipStream_t stream) {
    const float* hs = (const float*)d_in[0];
    const float* W  = (const float*)d_in[1];
    const float* b  = (const float*)d_in[2];

    float* out        = (float*)d_out;
    float* out_expert = out;                                      // [G,T,E] one-hot (as float)
    float* out_pmax   = out + (size_t)NTOKENS * NUM_EXPERTS;      // [G,T,1]
    float* out_logits = out_pmax + NTOKENS;                       // [G,T,E]
    int*   ws_idx     = (int*)d_ws;                               // [G*T] argmax expert ids

    router_logits_kernel<<<NTOKENS / 8, 256, 0, stream>>>(hs, W, b,
                                                          out_logits, out_pmax, ws_idx);
    router_scan_kernel<<<NGROUP, 256, 0, stream>>>(ws_idx, out_expert);
}